// Round 3
// baseline (349.022 us; speedup 1.0000x reference)
//
#include <hip/hip_runtime.h>
#include <math.h>

typedef unsigned short u16;
typedef __attribute__((ext_vector_type(8))) short bf16x8;
typedef __attribute__((ext_vector_type(4))) float floatx4;

__device__ __forceinline__ u16 f2bf(float f) {
  union { float f; unsigned int u; } c; c.f = f;
  return (u16)((c.u + 0x7FFFu + ((c.u >> 16) & 1u)) >> 16);
}

// load 8 contiguous elements as bf16x8 (identity for bf16, cvt for fp32)
__device__ __forceinline__ bf16x8 load8(const u16* p) { return *(const bf16x8*)p; }
__device__ __forceinline__ bf16x8 load8(const float* p) {
  float4 a = *(const float4*)p;
  float4 b = *(const float4*)(p + 4);
  bf16x8 r;
  r[0] = (short)f2bf(a.x); r[1] = (short)f2bf(a.y);
  r[2] = (short)f2bf(a.z); r[3] = (short)f2bf(a.w);
  r[4] = (short)f2bf(b.x); r[5] = (short)f2bf(b.y);
  r[6] = (short)f2bf(b.z); r[7] = (short)f2bf(b.w);
  return r;
}

__device__ __forceinline__ void store_c(u16* p, float v) { *p = f2bf(v); }
__device__ __forceinline__ void store_c(float* p, float v) { *p = v; }

// ---------------------------------------------------------------------------
// C(M,N) = A(M,K) @ B(N,K)^T   (A,B fp32 or bf16; C fp32 or bf16; fp32 accum)
// grid: (N/128, M/128), block 256 (4 waves, 2x2). All dims divisible.
// ---------------------------------------------------------------------------
template <typename TA, typename TB, typename TC>
__global__ __launch_bounds__(256) void gemm_bt(const TA* __restrict__ A,
                                               const TB* __restrict__ B,
                                               TC* __restrict__ C,
                                               int K, int N) {
  constexpr int BK = 64;
  constexpr int RS = BK + 8;  // +8 elem pad: rows r,r+8 alias -> 2-way (free)
  __shared__ __align__(16) u16 lds_a[128 * RS];
  __shared__ __align__(16) u16 lds_b[128 * RS];
  const int t = threadIdx.x;
  const int w = t >> 6, lane = t & 63, quad = lane >> 4, lr = lane & 15;
  const int wr = w >> 1, wc = w & 1;
  const int m0 = blockIdx.y * 128, n0 = blockIdx.x * 128;

  floatx4 acc[4][4];
#pragma unroll
  for (int i = 0; i < 4; ++i)
#pragma unroll
    for (int j = 0; j < 4; ++j) acc[i][j] = {0.f, 0.f, 0.f, 0.f};

  for (int k0 = 0; k0 < K; k0 += BK) {
    // stage A,B tiles (128 x 64 each): 1024 8-elem chunks / 256 threads = 4 each
#pragma unroll
    for (int i = 0; i < 4; ++i) {
      int c = t + i * 256;
      int row = c >> 3, col = (c & 7) * 8;
      *(bf16x8*)&lds_a[row * RS + col] = load8(&A[(size_t)(m0 + row) * K + k0 + col]);
      *(bf16x8*)&lds_b[row * RS + col] = load8(&B[(size_t)(n0 + row) * K + k0 + col]);
    }
    __syncthreads();
#pragma unroll
    for (int kk = 0; kk < 2; ++kk) {
      bf16x8 af[4], bfr[4];
#pragma unroll
      for (int mi = 0; mi < 4; ++mi)
        af[mi] = *(const bf16x8*)&lds_a[(wr * 64 + mi * 16 + lr) * RS + kk * 32 + quad * 8];
#pragma unroll
      for (int ni = 0; ni < 4; ++ni)
        bfr[ni] = *(const bf16x8*)&lds_b[(wc * 64 + ni * 16 + lr) * RS + kk * 32 + quad * 8];
#pragma unroll
      for (int mi = 0; mi < 4; ++mi)
#pragma unroll
        for (int ni = 0; ni < 4; ++ni)
          acc[mi][ni] = __builtin_amdgcn_mfma_f32_16x16x32_bf16(
              af[mi], bfr[ni], acc[mi][ni], 0, 0, 0);
    }
    __syncthreads();
  }
  // epilogue: C row = quad*4+r, col = lr  (m89-verified C/D layout)
#pragma unroll
  for (int mi = 0; mi < 4; ++mi)
#pragma unroll
    for (int r = 0; r < 4; ++r) {
      int m = m0 + wr * 64 + mi * 16 + quad * 4 + r;
#pragma unroll
      for (int ni = 0; ni < 4; ++ni) {
        int n = n0 + wc * 64 + ni * 16 + lr;
        store_c(&C[(size_t)m * N + n], acc[mi][ni][r]);
      }
    }
}

// ---------------------------------------------------------------------------
// Flash attention, causal. qkv: (N*S, 3E) bf16 rows; out: (N*S, E) bf16.
// grid: (S/128, N*H), block 256. Wave w owns q-rows [w*32, w*32+32).
// KV tile = 64. D = 64.
// ---------------------------------------------------------------------------
__global__ __launch_bounds__(256) void attn_fwd(const u16* __restrict__ qkv,
                                                u16* __restrict__ out) {
  constexpr int S = 2048, E = 1024, TE = 3072;
  constexpr float NEG = -1e30f;  // finite sentinel: no inf-inf NaN path
  __shared__ __align__(16) u16 lds_k[64 * 72];   // K[key][d]
  __shared__ __align__(16) u16 lds_vt[64 * 72];  // V^T[d][kv]
  __shared__ __align__(16) u16 lds_p[128 * 72];  // P[q][kv]
  const int t = threadIdx.x;
  const int w = t >> 6, lane = t & 63, quad = lane >> 4, lr = lane & 15;
  const int q0 = blockIdx.x * 128;
  const int b = blockIdx.y >> 4, h = blockIdx.y & 15;
  const size_t base = (size_t)b * S * TE;

  // Q fragments in registers (A-layout: m=lr, k=quad*8+j), reused all tiles
  bf16x8 qf[2][2];
#pragma unroll
  for (int mi = 0; mi < 2; ++mi)
#pragma unroll
    for (int kk = 0; kk < 2; ++kk) {
      int s = q0 + w * 32 + mi * 16 + lr;
      qf[mi][kk] = *(const bf16x8*)&qkv[base + (size_t)s * TE + h * 64 + kk * 32 + quad * 8];
    }

  float mstate[2][4], lstate[2][4];
  floatx4 oacc[2][4];
#pragma unroll
  for (int mi = 0; mi < 2; ++mi)
#pragma unroll
    for (int r = 0; r < 4; ++r) {
      mstate[mi][r] = NEG;
      lstate[mi][r] = 0.f;
    }
#pragma unroll
  for (int mi = 0; mi < 2; ++mi)
#pragma unroll
    for (int di = 0; di < 4; ++di) oacc[mi][di] = {0.f, 0.f, 0.f, 0.f};

  const int nkt = q0 / 64 + 2;  // causal: only KV tiles with kv_start <= q_max
  for (int kt = 0; kt < nkt; ++kt) {
    // stage K tile (64x64): 512 chunks / 256 thr = 2 each
#pragma unroll
    for (int i = 0; i < 2; ++i) {
      int c = t + i * 256;
      int row = c >> 3, col = (c & 7) * 8;
      *(bf16x8*)&lds_k[row * 72 + col] =
          *(const bf16x8*)&qkv[base + (size_t)(kt * 64 + row) * TE + E + h * 64 + col];
    }
    // stage V transposed: vector read, scalar LDS scatter
#pragma unroll
    for (int i = 0; i < 2; ++i) {
      int c = t + i * 256;
      int kv = c >> 3, d = (c & 7) * 8;
      bf16x8 v = *(const bf16x8*)&qkv[base + (size_t)(kt * 64 + kv) * TE + 2 * E + h * 64 + d];
#pragma unroll
      for (int j = 0; j < 8; ++j) lds_vt[(d + j) * 72 + kv] = (u16)v[j];
    }
    __syncthreads();

    // St = Q @ K^T  (C-layout: row=quad*4+r, col=lr)
    floatx4 st[2][4];
#pragma unroll
    for (int mi = 0; mi < 2; ++mi)
#pragma unroll
      for (int ni = 0; ni < 4; ++ni) st[mi][ni] = {0.f, 0.f, 0.f, 0.f};
#pragma unroll
    for (int kk = 0; kk < 2; ++kk) {
      bf16x8 kb[4];
#pragma unroll
      for (int ni = 0; ni < 4; ++ni)
        kb[ni] = *(const bf16x8*)&lds_k[(ni * 16 + lr) * 72 + kk * 32 + quad * 8];
#pragma unroll
      for (int mi = 0; mi < 2; ++mi)
#pragma unroll
        for (int ni = 0; ni < 4; ++ni)
          st[mi][ni] = __builtin_amdgcn_mfma_f32_16x16x32_bf16(
              qf[mi][kk], kb[ni], st[mi][ni], 0, 0, 0);
    }

    // online softmax (rows live in quad; 16-lane shuffle reduce)
#pragma unroll
    for (int mi = 0; mi < 2; ++mi)
#pragma unroll
      for (int r = 0; r < 4; ++r) {
        const int qrow = q0 + w * 32 + mi * 16 + quad * 4 + r;
        float tmax = NEG;
#pragma unroll
        for (int ni = 0; ni < 4; ++ni) {
          int kcol = kt * 64 + ni * 16 + lr;
          float v = st[mi][ni][r] * 0.125f;  // 1/sqrt(64)
          if (kcol > qrow) v = NEG;          // causal
          st[mi][ni][r] = v;
          tmax = fmaxf(tmax, v);
        }
#pragma unroll
        for (int off = 8; off >= 1; off >>= 1) tmax = fmaxf(tmax, __shfl_xor(tmax, off));
        float mnew = fmaxf(mstate[mi][r], tmax);
        float alpha = __expf(mstate[mi][r] - mnew);
        float rsum = 0.f;
#pragma unroll
        for (int ni = 0; ni < 4; ++ni) {
          float pv = __expf(st[mi][ni][r] - mnew);
          lds_p[(w * 32 + mi * 16 + quad * 4 + r) * 72 + ni * 16 + lr] = f2bf(pv);
          rsum += pv;
        }
#pragma unroll
        for (int off = 8; off >= 1; off >>= 1) rsum += __shfl_xor(rsum, off);
        lstate[mi][r] = lstate[mi][r] * alpha + rsum;
        mstate[mi][r] = mnew;
#pragma unroll
        for (int di = 0; di < 4; ++di) oacc[mi][di][r] *= alpha;
      }
    __syncthreads();  // P visible / lockstep

    // P back through LDS in A-operand layout (m120 pattern), then O += P@V
    bf16x8 pf[2][2];
#pragma unroll
    for (int mi = 0; mi < 2; ++mi)
#pragma unroll
      for (int kk = 0; kk < 2; ++kk)
        pf[mi][kk] = *(const bf16x8*)&lds_p[(w * 32 + mi * 16 + lr) * 72 + kk * 32 + quad * 8];
#pragma unroll
    for (int kk = 0; kk < 2; ++kk) {
      bf16x8 vb[4];
#pragma unroll
      for (int di = 0; di < 4; ++di)
        vb[di] = *(const bf16x8*)&lds_vt[(di * 16 + lr) * 72 + kk * 32 + quad * 8];
#pragma unroll
      for (int mi = 0; mi < 2; ++mi)
#pragma unroll
        for (int di = 0; di < 4; ++di)
          oacc[mi][di] = __builtin_amdgcn_mfma_f32_16x16x32_bf16(
              pf[mi][kk], vb[di], oacc[mi][di], 0, 0, 0);
    }
    __syncthreads();  // before K/Vt restage
  }

  // epilogue: O / l, write (N*S, E) bf16
#pragma unroll
  for (int mi = 0; mi < 2; ++mi)
#pragma unroll
    for (int r = 0; r < 4; ++r) {
      int s = q0 + w * 32 + mi * 16 + quad * 4 + r;
      float inv_l = 1.f / lstate[mi][r];
#pragma unroll
      for (int di = 0; di < 4; ++di)
        out[((size_t)(b * S + s)) * E + h * 64 + di * 16 + lr] =
            f2bf(oacc[mi][di][r] * inv_l);
    }
}

extern "C" void kernel_launch(void* const* d_in, const int* in_sizes, int n_in,
                              void* d_out, int out_size, void* d_ws, size_t ws_size,
                              hipStream_t stream) {
  constexpr int NB = 2, S = 2048, E = 1024;
  constexpr int M = NB * S;  // 4096
  const float* x = (const float*)d_in[0];      // fp32 per reference
  // d_in[1] = attn_mask (always causal tril; hardcoded in attn_fwd)
  const float* qkv_w = (const float*)d_in[2];  // fp32
  const float* o_w = (const float*)d_in[3];    // fp32
  float* out = (float*)d_out;                  // fp32 output (reference dtype)

  u16* qkv = (u16*)d_ws;                  // (M, 3E) bf16 = 25.2 MB
  u16* attn_o = qkv + (size_t)M * 3 * E;  // (M, E)  bf16 =  8.4 MB

  // 1) qkv = x @ qkv_w^T   (M=4096, N=3072, K=1024), fp32 in -> bf16 out
  gemm_bt<float, float, u16><<<dim3(3 * E / 128, M / 128), 256, 0, stream>>>(
      x, qkv_w, qkv, E, 3 * E);
  // 2) causal flash attention -> (M, E) bf16
  attn_fwd<<<dim3(S / 128, NB * 16), 256, 0, stream>>>(qkv, attn_o);
  // 3) out = attn_o @ o_w^T  (M=4096, N=1024, K=1024), A bf16, B fp32, C fp32
  gemm_bt<u16, float, float><<<dim3(E / 128, M / 128), 256, 0, stream>>>(
      attn_o, o_w, out, E, E);
}

// Round 4
// 300.234 us; speedup vs baseline: 1.1625x; 1.1625x over previous
//
#include <hip/hip_runtime.h>
#include <math.h>

typedef unsigned short u16;
typedef unsigned int uint;
typedef __attribute__((ext_vector_type(8))) short bf16x8;
typedef __attribute__((ext_vector_type(4))) float floatx4;

__device__ __forceinline__ u16 f2bf(float f) {
  union { float f; uint u; } c; c.f = f;
  return (u16)((c.u + 0x7FFFu + ((c.u >> 16) & 1u)) >> 16);
}
__device__ __forceinline__ float bf2f(u16 h) {
  union { uint u; float f; } c; c.u = ((uint)h) << 16;
  return c.f;
}

// async global->LDS, 16B per lane; LDS dest = wave-uniform base + lane*16
__device__ __forceinline__ void gl_lds16(const u16* g, u16* l) {
  __builtin_amdgcn_global_load_lds(
      (const __attribute__((address_space(1))) uint*)g,
      (__attribute__((address_space(3))) uint*)l, 16, 0, 0);
}

__device__ __forceinline__ void store_c(u16* p, float v) { *p = f2bf(v); }
__device__ __forceinline__ void store_c(float* p, float v) { *p = v; }

// ---------------------------------------------------------------------------
// fp32 -> bf16 elementwise; n must be divisible by 2048 (grid = n/2048)
// ---------------------------------------------------------------------------
__global__ __launch_bounds__(256) void cvt_bf16(const float* __restrict__ in,
                                                u16* __restrict__ out) {
  int i = (blockIdx.x * 256 + threadIdx.x) * 8;
  float4 a = *(const float4*)(in + i);
  float4 b = *(const float4*)(in + i + 4);
  bf16x8 r;
  r[0] = (short)f2bf(a.x); r[1] = (short)f2bf(a.y);
  r[2] = (short)f2bf(a.z); r[3] = (short)f2bf(a.w);
  r[4] = (short)f2bf(b.x); r[5] = (short)f2bf(b.y);
  r[6] = (short)f2bf(b.z); r[7] = (short)f2bf(b.w);
  *(bf16x8*)(out + i) = r;
}

// ---------------------------------------------------------------------------
// C(M,N) = A(M,K) @ B(N,K)^T, bf16 in, fp32 accum. m97-style:
// global_load_lds width=16 staging, XOR col-block swizzle for bank balance.
// LDS[row][cb] = global[row][cb ^ (row&7)]  (cb = 8-elem col block, BK=64)
// grid: (N/128, M/128), block 256 (4 waves, 2x2).
// ---------------------------------------------------------------------------
template <typename TC>
__global__ __launch_bounds__(256) void gemm_bt(const u16* __restrict__ A,
                                               const u16* __restrict__ B,
                                               TC* __restrict__ C,
                                               int K, int N) {
  __shared__ __align__(16) u16 lds_a[128 * 64];
  __shared__ __align__(16) u16 lds_b[128 * 64];
  const int t = threadIdx.x;
  const int w = t >> 6, lane = t & 63, quad = lane >> 4, lr = lane & 15;
  const int wr = w >> 1, wc = w & 1;
  const int m0 = blockIdx.y * 128, n0 = blockIdx.x * 128;

  // staging: lane l covers row (l>>3) of an 8-row chunk, global col block
  // (l&7) ^ (row&7); row&7 == l>>3 since chunk bases are multiples of 8.
  const int srow = lane >> 3;
  const int scol = ((lane & 7) ^ srow) * 8;
  const u16* Ab = A + (size_t)(m0 + w * 32 + srow) * K + scol;
  const u16* Bb = B + (size_t)(n0 + w * 32 + srow) * K + scol;
  u16* la = lds_a + (w * 32) * 64;
  u16* lb = lds_b + (w * 32) * 64;

  floatx4 acc[4][4];
#pragma unroll
  for (int i = 0; i < 4; ++i)
#pragma unroll
    for (int j = 0; j < 4; ++j) acc[i][j] = {0.f, 0.f, 0.f, 0.f};

  for (int k0 = 0; k0 < K; k0 += 64) {
#pragma unroll
    for (int j = 0; j < 4; ++j) {
      gl_lds16(Ab + (size_t)(j * 8) * K + k0, la + j * 8 * 64);
      gl_lds16(Bb + (size_t)(j * 8) * K + k0, lb + j * 8 * 64);
    }
    __syncthreads();  // drains vmcnt(0): LDS tiles complete
#pragma unroll
    for (int kk = 0; kk < 2; ++kk) {
      bf16x8 af[4], bfr[4];
#pragma unroll
      for (int mi = 0; mi < 4; ++mi)
        af[mi] = *(const bf16x8*)&lds_a[(wr * 64 + mi * 16 + lr) * 64 +
                                        (((kk * 4 + quad) ^ (lr & 7)) * 8)];
#pragma unroll
      for (int ni = 0; ni < 4; ++ni)
        bfr[ni] = *(const bf16x8*)&lds_b[(wc * 64 + ni * 16 + lr) * 64 +
                                         (((kk * 4 + quad) ^ (lr & 7)) * 8)];
#pragma unroll
      for (int mi = 0; mi < 4; ++mi)
#pragma unroll
        for (int ni = 0; ni < 4; ++ni)
          acc[mi][ni] = __builtin_amdgcn_mfma_f32_16x16x32_bf16(
              af[mi], bfr[ni], acc[mi][ni], 0, 0, 0);
    }
    __syncthreads();
  }
  // epilogue: C row = quad*4+r, col = lr (m89-verified layout)
#pragma unroll
  for (int mi = 0; mi < 4; ++mi)
#pragma unroll
    for (int r = 0; r < 4; ++r) {
      int m = m0 + wr * 64 + mi * 16 + quad * 4 + r;
#pragma unroll
      for (int ni = 0; ni < 4; ++ni) {
        int n = n0 + wc * 64 + ni * 16 + lr;
        store_c(&C[(size_t)m * N + n], acc[mi][ni][r]);
      }
    }
}

// ---------------------------------------------------------------------------
// Flash attention, causal. qkv: (NB*S, 3E) bf16; out: (NB*S, E) bf16.
// grid: (S/64, NB*H) = (32, 32), block 256. Wave w owns q-rows [w*16, w*16+16).
// KV tile 64. 2 barriers/tile (K,V^T shared; P wave-private).
// V^T and P use XOR block swizzle s = ((row>>3)+(row&7))&7 -> bank-balanced.
// ---------------------------------------------------------------------------
__global__ __launch_bounds__(256) void attn_fwd(const u16* __restrict__ qkv,
                                                u16* __restrict__ out) {
  constexpr int S = 2048, E = 1024, TE = 3072;
  constexpr float NEG = -1e30f;
  __shared__ __align__(16) u16 lds_k[64 * 72];   // K[key][d], stride 72 (balanced)
  __shared__ __align__(16) u16 lds_vt[64 * 64];  // V^T[d][kv], swizzled blocks
  __shared__ __align__(16) u16 lds_p[64 * 64];   // P[q][kv], swizzled blocks
  const int t = threadIdx.x;
  const int w = t >> 6, lane = t & 63, quad = lane >> 4, lr = lane & 15;
  const int qt = blockIdx.x;
  const int q0 = qt * 64;
  const int b = blockIdx.y >> 4, h = blockIdx.y & 15;
  const size_t base = (size_t)b * S * TE;

  // Q fragments (A-layout m=lr, k=quad*8+j), pre-scaled by 1/8 (exact in bf16)
  bf16x8 qf[2];
#pragma unroll
  for (int kk = 0; kk < 2; ++kk) {
    bf16x8 q = *(const bf16x8*)&qkv[base + (size_t)(q0 + w * 16 + lr) * TE +
                                    h * 64 + kk * 32 + quad * 8];
#pragma unroll
    for (int j = 0; j < 8; ++j) q[j] = (short)f2bf(bf2f((u16)q[j]) * 0.125f);
    qf[kk] = q;
  }

  float mst[4], lst[4];
  floatx4 oacc[4];
#pragma unroll
  for (int r = 0; r < 4; ++r) { mst[r] = NEG; lst[r] = 0.f; }
#pragma unroll
  for (int di = 0; di < 4; ++di) oacc[di] = {0.f, 0.f, 0.f, 0.f};

  for (int kt = 0; kt <= qt; ++kt) {
    const u16* kbase = &qkv[base + (size_t)(kt * 64) * TE + E + h * 64];
    const u16* vbase = &qkv[base + (size_t)(kt * 64) * TE + 2 * E + h * 64];
    // K tile (64x64), row-major stride 72
#pragma unroll
    for (int i = 0; i < 2; ++i) {
      int c = t + i * 256;
      int row = c >> 3, cb = c & 7;
      *(bf16x8*)&lds_k[row * 72 + cb * 8] =
          *(const bf16x8*)&kbase[(size_t)row * TE + cb * 8];
    }
    // V^T swizzled: V[kv][d] -> lds_vt[d*64 + ((kv>>3 ^ s(d))*8 + (kv&7))]
#pragma unroll
    for (int i = 0; i < 2; ++i) {
      int c = t + i * 256;
      int kv = c >> 3, d0 = (c & 7) * 8;
      bf16x8 v = *(const bf16x8*)&vbase[(size_t)kv * TE + d0];
      int kvb = kv >> 3, kvo = kv & 7;
#pragma unroll
      for (int j = 0; j < 8; ++j) {
        int s = ((c & 7) + j) & 7;  // ((d>>3)+(d&7))&7 with d=d0+j
        lds_vt[(d0 + j) * 64 + (((kvb ^ s) << 3) + kvo)] = (u16)v[j];
      }
    }
    __syncthreads();

    // St = Q @ K^T (C-layout: row=quad*4+r, col=lr)
    floatx4 st[4];
#pragma unroll
    for (int ni = 0; ni < 4; ++ni) st[ni] = {0.f, 0.f, 0.f, 0.f};
#pragma unroll
    for (int kk = 0; kk < 2; ++kk) {
      bf16x8 kb[4];
#pragma unroll
      for (int ni = 0; ni < 4; ++ni)
        kb[ni] = *(const bf16x8*)&lds_k[(ni * 16 + lr) * 72 + kk * 32 + quad * 8];
#pragma unroll
      for (int ni = 0; ni < 4; ++ni)
        st[ni] = __builtin_amdgcn_mfma_f32_16x16x32_bf16(qf[kk], kb[ni], st[ni], 0, 0, 0);
    }

    const bool diag = (kt == qt);  // wave-uniform
#pragma unroll
    for (int r = 0; r < 4; ++r) {
      const int rl = w * 16 + quad * 4 + r;  // local q-row in [0,64)
      if (diag) {
#pragma unroll
        for (int ni = 0; ni < 4; ++ni)
          if (ni * 16 + lr > rl) st[ni][r] = NEG;
      }
      float tmax = NEG;
#pragma unroll
      for (int ni = 0; ni < 4; ++ni) tmax = fmaxf(tmax, st[ni][r]);
#pragma unroll
      for (int off = 8; off >= 1; off >>= 1) tmax = fmaxf(tmax, __shfl_xor(tmax, off));
      float mnew = fmaxf(mst[r], tmax);
      float alpha = __expf(mst[r] - mnew);
      float rsum = 0.f;
      const int sp = ((rl >> 3) + (rl & 7)) & 7;
#pragma unroll
      for (int ni = 0; ni < 4; ++ni) {
        float pv = __expf(st[ni][r] - mnew);
        rsum += pv;
        lds_p[rl * 64 + (((((ni << 1) + (lr >> 3)) ^ sp) << 3) + (lr & 7))] = f2bf(pv);
      }
#pragma unroll
      for (int off = 8; off >= 1; off >>= 1) rsum += __shfl_xor(rsum, off);
      lst[r] = lst[r] * alpha + rsum;
      mst[r] = mnew;
#pragma unroll
      for (int di = 0; di < 4; ++di) oacc[di][r] *= alpha;
    }
    // P wave-private: no barrier needed (compiler inserts lgkmcnt waits)

    // O += P @ V  (A = P from LDS in A-layout, B = V^T)
#pragma unroll
    for (int kk = 0; kk < 2; ++kk) {
      const int rl = w * 16 + lr;
      const int sp = ((rl >> 3) + (rl & 7)) & 7;
      bf16x8 pf = *(const bf16x8*)&lds_p[rl * 64 + ((((kk << 2) + quad) ^ sp) << 3)];
      bf16x8 vb[4];
#pragma unroll
      for (int di = 0; di < 4; ++di) {
        int d = di * 16 + lr;
        int s = ((d >> 3) + (d & 7)) & 7;
        vb[di] = *(const bf16x8*)&lds_vt[d * 64 + ((((kk << 2) + quad) ^ s) << 3)];
      }
#pragma unroll
      for (int di = 0; di < 4; ++di)
        oacc[di] = __builtin_amdgcn_mfma_f32_16x16x32_bf16(pf, vb[di], oacc[di], 0, 0, 0);
    }
    __syncthreads();  // K/Vt consumed before restage
  }

#pragma unroll
  for (int r = 0; r < 4; ++r) {
    int sg = q0 + w * 16 + quad * 4 + r;
    float inv_l = 1.f / lst[r];
#pragma unroll
    for (int di = 0; di < 4; ++di)
      out[((size_t)(b * S + sg)) * E + h * 64 + di * 16 + lr] =
          f2bf(oacc[di][r] * inv_l);
  }
}

extern "C" void kernel_launch(void* const* d_in, const int* in_sizes, int n_in,
                              void* d_out, int out_size, void* d_ws, size_t ws_size,
                              hipStream_t stream) {
  constexpr int NB = 2, S = 2048, E = 1024;
  constexpr int M = NB * S;  // 4096
  const float* x = (const float*)d_in[0];
  // d_in[1] = attn_mask (always causal tril; hardcoded)
  const float* qkv_w = (const float*)d_in[2];
  const float* o_w = (const float*)d_in[3];
  float* out = (float*)d_out;

  u16* qkv = (u16*)d_ws;                       // (M, 3E) bf16  25.2 MB
  u16* attn_o = qkv + (size_t)M * 3 * E;       // (M, E)  bf16   8.4 MB
  u16* xb = attn_o + (size_t)M * E;            // (M, E)  bf16   8.4 MB
  u16* wb = xb + (size_t)M * E;                // (3E, E) bf16   6.3 MB
  u16* ob = wb + (size_t)3 * E * E;            // (E, E)  bf16   2.1 MB

  // 0) fp32 -> bf16 conversions (memory-bound, ~10 us total)
  cvt_bf16<<<M * E / 2048, 256, 0, stream>>>(x, xb);
  cvt_bf16<<<3 * E * E / 2048, 256, 0, stream>>>(qkv_w, wb);
  cvt_bf16<<<E * E / 2048, 256, 0, stream>>>(o_w, ob);
  // 1) qkv = x @ qkv_w^T  (4096 x 3072 x 1024)
  gemm_bt<u16><<<dim3(3 * E / 128, M / 128), 256, 0, stream>>>(xb, wb, qkv, E, 3 * E);
  // 2) causal flash attention
  attn_fwd<<<dim3(S / 64, NB * 16), 256, 0, stream>>>(qkv, attn_o);
  // 3) out = attn_o @ o_w^T  (4096 x 1024 x 1024), fp32 out
  gemm_bt<float><<<dim3(E / 128, M / 128), 256, 0, stream>>>(attn_o, ob, out, E, E);
}

// Round 5
// 219.498 us; speedup vs baseline: 1.5901x; 1.3678x over previous
//
#include <hip/hip_runtime.h>
#include <math.h>

typedef unsigned short u16;
typedef unsigned int uint;
typedef __attribute__((ext_vector_type(8))) short bf16x8;
typedef __attribute__((ext_vector_type(4))) float floatx4;

__device__ __forceinline__ u16 f2bf(float f) {
  union { float f; uint u; } c; c.f = f;
  return (u16)((c.u + 0x7FFFu + ((c.u >> 16) & 1u)) >> 16);
}
__device__ __forceinline__ float bf2f(u16 h) {
  union { uint u; float f; } c; c.u = ((uint)h) << 16;
  return c.f;
}

// async global->LDS, 16B per lane; LDS dest = wave-uniform base + lane*16
__device__ __forceinline__ void gl_lds16(const u16* g, u16* l) {
  __builtin_amdgcn_global_load_lds(
      (const __attribute__((address_space(1))) uint*)g,
      (__attribute__((address_space(3))) uint*)l, 16, 0, 0);
}

__device__ __forceinline__ void store_c(u16* p, float v) { *p = f2bf(v); }
__device__ __forceinline__ void store_c(float* p, float v) { *p = v; }

// 16-lane all-reduce via DPP row_ror (VALU pipe, not LDS)
#define ROR16(x, n)                                                        \
  __builtin_bit_cast(float, __builtin_amdgcn_update_dpp(                   \
      __builtin_bit_cast(int, (x)), __builtin_bit_cast(int, (x)),          \
      0x120 + (n), 0xF, 0xF, false))
__device__ __forceinline__ float rmax16(float x) {
  x = fmaxf(x, ROR16(x, 8)); x = fmaxf(x, ROR16(x, 4));
  x = fmaxf(x, ROR16(x, 2)); x = fmaxf(x, ROR16(x, 1));
  return x;
}
__device__ __forceinline__ float rsum16(float x) {
  x += ROR16(x, 8); x += ROR16(x, 4); x += ROR16(x, 2); x += ROR16(x, 1);
  return x;
}

// ---------------------------------------------------------------------------
// fp32 -> bf16 elementwise; n divisible by 2048 (grid = n/2048)
// ---------------------------------------------------------------------------
__global__ __launch_bounds__(256) void cvt_bf16(const float* __restrict__ in,
                                                u16* __restrict__ out) {
  int i = (blockIdx.x * 256 + threadIdx.x) * 8;
  float4 a = *(const float4*)(in + i);
  float4 b = *(const float4*)(in + i + 4);
  bf16x8 r;
  r[0] = (short)f2bf(a.x); r[1] = (short)f2bf(a.y);
  r[2] = (short)f2bf(a.z); r[3] = (short)f2bf(a.w);
  r[4] = (short)f2bf(b.x); r[5] = (short)f2bf(b.y);
  r[6] = (short)f2bf(b.z); r[7] = (short)f2bf(b.w);
  *(bf16x8*)(out + i) = r;
}

// ---------------------------------------------------------------------------
// One-time V transpose: qkv V-part -> vt[bh][d][kv]  (32, 64, 2048)
// grid (S/64, 32), block 256
// ---------------------------------------------------------------------------
__global__ __launch_bounds__(256) void vtrans(const u16* __restrict__ qkv,
                                              u16* __restrict__ vt) {
  constexpr int S = 2048, E = 1024, TE = 3072;
  __shared__ u16 tile[64 * 72];
  const int t = threadIdx.x;
  const int kv0 = blockIdx.x * 64;
  const int bh = blockIdx.y, b = bh >> 4, h = bh & 15;
  const u16* src = qkv + (size_t)b * S * TE + 2 * E + h * 64;
#pragma unroll
  for (int i = 0; i < 2; ++i) {
    int c = t + i * 256;
    int kv = c >> 3, d0 = (c & 7) * 8;
    *(bf16x8*)&tile[kv * 72 + d0] = *(const bf16x8*)&src[(size_t)(kv0 + kv) * TE + d0];
  }
  __syncthreads();
  u16* dst = vt + (size_t)bh * 64 * S + kv0;
#pragma unroll
  for (int i = 0; i < 2; ++i) {
    int c = t + i * 256;
    int d = c >> 3, k0 = (c & 7) * 8;
    bf16x8 r;
#pragma unroll
    for (int j = 0; j < 8; ++j) r[j] = tile[(k0 + j) * 72 + d];
    *(bf16x8*)&dst[(size_t)d * S + k0] = r;
  }
}

// ---------------------------------------------------------------------------
// C(M,N) = A(M,K) @ B(N,K)^T, bf16 in, fp32 accum (m97 structure + XOR swizzle)
// grid: (N/128, M/128), block 256.
// ---------------------------------------------------------------------------
template <typename TC>
__global__ __launch_bounds__(256) void gemm_bt(const u16* __restrict__ A,
                                               const u16* __restrict__ B,
                                               TC* __restrict__ C,
                                               int K, int N) {
  __shared__ __align__(16) u16 lds_a[128 * 64];
  __shared__ __align__(16) u16 lds_b[128 * 64];
  const int t = threadIdx.x;
  const int w = t >> 6, lane = t & 63, quad = lane >> 4, lr = lane & 15;
  const int wr = w >> 1, wc = w & 1;
  const int m0 = blockIdx.y * 128, n0 = blockIdx.x * 128;

  const int srow = lane >> 3;
  const int scol = ((lane & 7) ^ srow) * 8;
  const u16* Ab = A + (size_t)(m0 + w * 32 + srow) * K + scol;
  const u16* Bb = B + (size_t)(n0 + w * 32 + srow) * K + scol;
  u16* la = lds_a + (w * 32) * 64;
  u16* lb = lds_b + (w * 32) * 64;

  floatx4 acc[4][4];
#pragma unroll
  for (int i = 0; i < 4; ++i)
#pragma unroll
    for (int j = 0; j < 4; ++j) acc[i][j] = {0.f, 0.f, 0.f, 0.f};

  for (int k0 = 0; k0 < K; k0 += 64) {
#pragma unroll
    for (int j = 0; j < 4; ++j) {
      gl_lds16(Ab + (size_t)(j * 8) * K + k0, la + j * 8 * 64);
      gl_lds16(Bb + (size_t)(j * 8) * K + k0, lb + j * 8 * 64);
    }
    __syncthreads();
#pragma unroll
    for (int kk = 0; kk < 2; ++kk) {
      bf16x8 af[4], bfr[4];
#pragma unroll
      for (int mi = 0; mi < 4; ++mi)
        af[mi] = *(const bf16x8*)&lds_a[(wr * 64 + mi * 16 + lr) * 64 +
                                        (((kk * 4 + quad) ^ (lr & 7)) * 8)];
#pragma unroll
      for (int ni = 0; ni < 4; ++ni)
        bfr[ni] = *(const bf16x8*)&lds_b[(wc * 64 + ni * 16 + lr) * 64 +
                                         (((kk * 4 + quad) ^ (lr & 7)) * 8)];
#pragma unroll
      for (int mi = 0; mi < 4; ++mi)
#pragma unroll
        for (int ni = 0; ni < 4; ++ni)
          acc[mi][ni] = __builtin_amdgcn_mfma_f32_16x16x32_bf16(
              af[mi], bfr[ni], acc[mi][ni], 0, 0, 0);
    }
    __syncthreads();
  }
#pragma unroll
  for (int mi = 0; mi < 4; ++mi)
#pragma unroll
    for (int r = 0; r < 4; ++r) {
      int m = m0 + wr * 64 + mi * 16 + quad * 4 + r;
#pragma unroll
      for (int ni = 0; ni < 4; ++ni) {
        int n = n0 + wc * 64 + ni * 16 + lr;
        store_c(&C[(size_t)m * N + n], acc[mi][ni][r]);
      }
    }
}

// ---------------------------------------------------------------------------
// Flash attention, causal. Paired q-tiles (bx, 31-bx) -> uniform 33 KV-tiles.
// Async double-buffered K/V^T staging; DPP reductions; 1 barrier/tile.
// grid (16, 32), block 256. Wave w owns q-rows [w*16, w*16+16).
// ---------------------------------------------------------------------------
__global__ __launch_bounds__(256) void attn_fwd(const u16* __restrict__ qkv,
                                                const u16* __restrict__ vt,
                                                u16* __restrict__ out) {
  constexpr int S = 2048, E = 1024, TE = 3072;
  constexpr float NEG = -1e30f;
  __shared__ __align__(16) u16 lds_k[2][64 * 64];   // K[key][d], col-swizzled
  __shared__ __align__(16) u16 lds_vt[2][64 * 64];  // V^T[d][kv], col-swizzled
  __shared__ __align__(16) u16 lds_p[64 * 64];      // P[q][kv], sp-swizzled
  const int t = threadIdx.x;
  const int w = t >> 6, lane = t & 63, quad = lane >> 4, lr = lane & 15;
  const int b = blockIdx.y >> 4, h = blockIdx.y & 15;
  const size_t base = (size_t)b * S * TE;
  const u16* kbase = qkv + base + E + h * 64;
  const u16* vtb = vt + (size_t)blockIdx.y * 64 * S;

  const int srow = lane >> 3;                // row within 8-row group
  const int scol = ((lane & 7) ^ srow) * 8;  // permuted col block (XOR swizzle)

  for (int ph = 0; ph < 2; ++ph) {
    const int qt = ph ? (31 - (int)blockIdx.x) : (int)blockIdx.x;
    const int q0 = qt * 64;
    const int nkt = qt + 1;

    // Q fragments (A-layout m=lr, k=quad*8+j), pre-scaled by 1/8 (bf16-exact)
    bf16x8 qf[2];
#pragma unroll
    for (int kk = 0; kk < 2; ++kk) {
      bf16x8 q = *(const bf16x8*)&qkv[base + (size_t)(q0 + w * 16 + lr) * TE +
                                      h * 64 + kk * 32 + quad * 8];
#pragma unroll
      for (int j = 0; j < 8; ++j) q[j] = (short)f2bf(bf2f((u16)q[j]) * 0.125f);
      qf[kk] = q;
    }

    float mst[4], lst[4];
    floatx4 oacc[4];
#pragma unroll
    for (int r = 0; r < 4; ++r) { mst[r] = NEG; lst[r] = 0.f; }
#pragma unroll
    for (int di = 0; di < 4; ++di) oacc[di] = {0.f, 0.f, 0.f, 0.f};

    __syncthreads();  // previous phase done with LDS buffers
    // issue tile 0 async loads
#pragma unroll
    for (int i = 0; i < 2; ++i) {
      int r0 = w * 8 + i * 32;
      gl_lds16(kbase + (size_t)(r0 + srow) * TE + scol, &lds_k[0][r0 * 64]);
      gl_lds16(vtb + (size_t)(r0 + srow) * S + scol, &lds_vt[0][r0 * 64]);
    }

    for (int kt = 0; kt < nkt; ++kt) {
      const int bi = kt & 1;
      __syncthreads();  // drains tile-kt loads (issued last iter, overlapped)
      if (kt + 1 < nkt) {
        const int bn = bi ^ 1;
#pragma unroll
        for (int i = 0; i < 2; ++i) {
          int r0 = w * 8 + i * 32;
          gl_lds16(kbase + (size_t)((kt + 1) * 64 + r0 + srow) * TE + scol,
                   &lds_k[bn][r0 * 64]);
          gl_lds16(vtb + (size_t)(r0 + srow) * S + (kt + 1) * 64 + scol,
                   &lds_vt[bn][r0 * 64]);
        }
      }

      // St = Q @ K^T (C-layout: row=quad*4+r, col=lr)
      floatx4 st[4];
#pragma unroll
      for (int ni = 0; ni < 4; ++ni) st[ni] = {0.f, 0.f, 0.f, 0.f};
#pragma unroll
      for (int kk = 0; kk < 2; ++kk) {
        bf16x8 kb[4];
#pragma unroll
        for (int ni = 0; ni < 4; ++ni)
          kb[ni] = *(const bf16x8*)&lds_k[bi][(ni * 16 + lr) * 64 +
                                             (((kk * 4 + quad) ^ (lr & 7)) * 8)];
#pragma unroll
        for (int ni = 0; ni < 4; ++ni)
          st[ni] = __builtin_amdgcn_mfma_f32_16x16x32_bf16(qf[kk], kb[ni], st[ni], 0, 0, 0);
      }

      const bool diag = (kt == qt);  // wave-uniform
#pragma unroll
      for (int r = 0; r < 4; ++r) {
        const int rl = w * 16 + quad * 4 + r;
        if (diag) {
#pragma unroll
          for (int ni = 0; ni < 4; ++ni)
            if (ni * 16 + lr > rl) st[ni][r] = NEG;
        }
        float tmax = fmaxf(fmaxf(st[0][r], st[1][r]), fmaxf(st[2][r], st[3][r]));
        tmax = rmax16(tmax);
        float mnew = fmaxf(mst[r], tmax);
        float alpha = __expf(mst[r] - mnew);
        float rsum = 0.f;
        const int sp = ((rl >> 3) + (rl & 7)) & 7;
#pragma unroll
        for (int ni = 0; ni < 4; ++ni) {
          float pv = __expf(st[ni][r] - mnew);
          rsum += pv;
          lds_p[rl * 64 + (((((ni << 1) + (lr >> 3)) ^ sp) << 3) + (lr & 7))] = f2bf(pv);
        }
        rsum = rsum16(rsum);
        lst[r] = lst[r] * alpha + rsum;
        mst[r] = mnew;
#pragma unroll
        for (int di = 0; di < 4; ++di) oacc[di][r] *= alpha;
      }
      // P is wave-private (rows w*16..w*16+15): no barrier needed

      // O += P @ V
#pragma unroll
      for (int kk = 0; kk < 2; ++kk) {
        const int rl2 = w * 16 + lr;
        const int sp2 = ((rl2 >> 3) + (rl2 & 7)) & 7;
        bf16x8 pf = *(const bf16x8*)&lds_p[rl2 * 64 + ((((kk << 2) + quad) ^ sp2) << 3)];
        bf16x8 vb[4];
#pragma unroll
        for (int di = 0; di < 4; ++di)
          vb[di] = *(const bf16x8*)&lds_vt[bi][(di * 16 + lr) * 64 +
                                              (((kk * 4 + quad) ^ (lr & 7)) * 8)];
#pragma unroll
        for (int di = 0; di < 4; ++di)
          oacc[di] = __builtin_amdgcn_mfma_f32_16x16x32_bf16(pf, vb[di], oacc[di], 0, 0, 0);
      }
    }

    // epilogue: O / l
#pragma unroll
    for (int r = 0; r < 4; ++r) {
      int sg = q0 + w * 16 + quad * 4 + r;
      float inv_l = 1.f / lst[r];
#pragma unroll
      for (int di = 0; di < 4; ++di)
        out[((size_t)(b * S + sg)) * E + h * 64 + di * 16 + lr] =
            f2bf(oacc[di][r] * inv_l);
    }
  }
}

extern "C" void kernel_launch(void* const* d_in, const int* in_sizes, int n_in,
                              void* d_out, int out_size, void* d_ws, size_t ws_size,
                              hipStream_t stream) {
  constexpr int NB = 2, S = 2048, E = 1024;
  constexpr int M = NB * S;  // 4096
  const float* x = (const float*)d_in[0];
  // d_in[1] = attn_mask (always causal tril; hardcoded)
  const float* qkv_w = (const float*)d_in[2];
  const float* o_w = (const float*)d_in[3];
  float* out = (float*)d_out;

  u16* qkv = (u16*)d_ws;                     // 25.2 MB
  u16* vt = qkv + (size_t)M * 3 * E;         //  8.4 MB  vt[32][64][2048]
  u16* xb = vt + (size_t)32 * 64 * S;        //  8.4 MB (reused as attn_o)
  u16* attn_o = xb;                          //  alias: xb dead after gemm1
  u16* wb = xb + (size_t)M * E;              //  6.3 MB
  u16* ob = wb + (size_t)3 * E * E;          //  2.1 MB   total 50.4 MB

  cvt_bf16<<<M * E / 2048, 256, 0, stream>>>(x, xb);
  cvt_bf16<<<3 * E * E / 2048, 256, 0, stream>>>(qkv_w, wb);
  cvt_bf16<<<E * E / 2048, 256, 0, stream>>>(o_w, ob);
  // 1) qkv = x @ qkv_w^T  (4096 x 3072 x 1024)
  gemm_bt<u16><<<dim3(3 * E / 128, M / 128), 256, 0, stream>>>(xb, wb, qkv, E, 3 * E);
  // 1b) one-time V transpose
  vtrans<<<dim3(S / 64, NB * 16), 256, 0, stream>>>(qkv, vt);
  // 2) causal flash attention (paired q-tiles)
  attn_fwd<<<dim3(16, NB * 16), 256, 0, stream>>>(qkv, vt, attn_o);
  // 3) out = attn_o @ o_w^T  (4096 x 1024 x 1024), fp32 out
  gemm_bt<float><<<dim3(E / 128, M / 128), 256, 0, stream>>>(attn_o, ob, out, E, E);
}